// Round 5
// baseline (226.101 us; speedup 1.0000x reference)
//
#include <hip/hip_runtime.h>
#include <hip/hip_bf16.h>

#define NN 4096
#define BB 512

typedef __attribute__((ext_vector_type(8))) short short8;   // 8 bf16 (4 VGPRs)
typedef __attribute__((ext_vector_type(4))) float f32x4;    // MFMA C/D frag
typedef unsigned short ushort;
typedef __attribute__((ext_vector_type(4))) ushort ushort4v;

__device__ __forceinline__ float scal_val(const void* p) {
    int b = *(const int*)p;
    if (b >= 1 && b <= 1000000) return (float)b;
    return __int_as_float(b);
}

// f32 -> bf16 bits, round-to-nearest-even (inputs are finite positive here)
__device__ __forceinline__ ushort f2bf(float x) {
    unsigned u = __float_as_uint(x);
    u += 0x7fffu + ((u >> 16) & 1u);
    return (ushort)(u >> 16);
}

__device__ __forceinline__ void gload16(const void* g, void* l) {
    __builtin_amdgcn_global_load_lds(
        (const __attribute__((address_space(1))) unsigned int*)g,
        (__attribute__((address_space(3))) unsigned int*)l, 16, 0, 0);
}

__device__ __forceinline__ double wave_sum(double v) {
#pragma unroll
    for (int s = 32; s > 0; s >>= 1) v += __shfl_down(v, s, 64);
    return v;
}

// Partials layout (doubles): [0,512) t1 | [512,1024) t2 | [1024,1536) t3
// | [1536,2560) kl.  Every slot written every call (no memset needed).

// ---------------------------------------------------------------------------
// Merged prep. Blocks [0,4096): K -> Kb (bf16) + KTb (bf16 transposed).
// Blocks [4096,4608): U -> fT, gT (bf16, transposed [j][k]).
// ---------------------------------------------------------------------------
__global__ __launch_bounds__(256) void k_prep(const float* __restrict__ K,
                                              const float* __restrict__ U,
                                              ushort* __restrict__ Kb,
                                              ushort* __restrict__ KTb,
                                              ushort* __restrict__ fT,
                                              ushort* __restrict__ gT,
                                              const void* epsp, const void* lamp) {
    __shared__ float tile[64][65];
    __shared__ float tg[64][65];
    const int t = threadIdx.x;
    const int tx = t & 15, ty = t >> 4;
    const int bid = blockIdx.x;

    if (bid < 4096) {
        const int c0 = (bid & 63) * 64, r0 = (bid >> 6) * 64;
#pragma unroll
        for (int it = 0; it < 4; ++it) {
            int row = ty + it * 16;
            float4 v = *(const float4*)&K[(size_t)(r0 + row) * NN + c0 + tx * 4];
            ushort4v o = {f2bf(v.x), f2bf(v.y), f2bf(v.z), f2bf(v.w)};
            *(ushort4v*)&Kb[(size_t)(r0 + row) * NN + c0 + tx * 4] = o;
            tile[row][tx * 4 + 0] = v.x;
            tile[row][tx * 4 + 1] = v.y;
            tile[row][tx * 4 + 2] = v.z;
            tile[row][tx * 4 + 3] = v.w;
        }
        __syncthreads();
#pragma unroll
        for (int it = 0; it < 4; ++it) {
            int row = ty + it * 16;  // col within tile -> KT row (c0+row)
            ushort4v o = {f2bf(tile[tx * 4 + 0][row]), f2bf(tile[tx * 4 + 1][row]),
                          f2bf(tile[tx * 4 + 2][row]), f2bf(tile[tx * 4 + 3][row])};
            *(ushort4v*)&KTb[(size_t)(c0 + row) * NN + r0 + tx * 4] = o;
        }
    } else {
        const int r = bid - 4096;
        const int c0 = (r & 7) * 64;   // U col tile (j)
        const int r0 = (r >> 3) * 64;  // U row tile (k)
        const float eps = scal_val(epsp), lam = scal_val(lamp);
        const float rr = lam / eps;
#pragma unroll
        for (int it = 0; it < 4; ++it) {
            int row = ty + it * 16;
            float4 v = *(const float4*)&U[(size_t)(r0 + row) * BB + c0 + tx * 4];
            float uu[4] = {v.x, v.y, v.z, v.w};
#pragma unroll
            for (int k = 0; k < 4; ++k) {
                float L = __logf(lam / (lam - uu[k]));
                float fl = rr * L;
                float fv = __expf(fl);
                tile[row][tx * 4 + k] = fv;
                tg[row][tx * 4 + k] = fv * fl;
            }
        }
        __syncthreads();
#pragma unroll
        for (int it = 0; it < 4; ++it) {
            int row = ty + it * 16;
            ushort4v of = {f2bf(tile[tx * 4 + 0][row]), f2bf(tile[tx * 4 + 1][row]),
                           f2bf(tile[tx * 4 + 2][row]), f2bf(tile[tx * 4 + 3][row])};
            ushort4v og = {f2bf(tg[tx * 4 + 0][row]), f2bf(tg[tx * 4 + 1][row]),
                           f2bf(tg[tx * 4 + 2][row]), f2bf(tg[tx * 4 + 3][row])};
            *(ushort4v*)&fT[(size_t)(c0 + row) * NN + r0 + tx * 4] = of;
            *(ushort4v*)&gT[(size_t)(c0 + row) * NN + r0 + tx * 4] = og;
        }
    }
}

// ---------------------------------------------------------------------------
// GEMM1 (MFMA, dual, FULL K, fused epilogue): Y1=Kb@f, Y2=Kb@g on a 64x64
// tile (4 waves, wave=32x32 as 2x2 16x16 frags), BK=64, dbuf, XOR swizzle.
// Epilogue in-kernel: a=P/Y1; t1+=a*Y2, t2+=P*log(a), t3+=P; aT via LDS
// transpose.  Grid 512 (2 blocks/CU).  j-panel = bid&7 -> per-XCD L2 reuse.
// ---------------------------------------------------------------------------
__global__ __launch_bounds__(256) void k_gemm1(const ushort* __restrict__ Kb,
                                               const ushort* __restrict__ fT,
                                               const ushort* __restrict__ gT,
                                               const float* __restrict__ P,
                                               ushort* __restrict__ aT,
                                               double* __restrict__ parts) {
    __shared__ __align__(16) ushort As[2][64 * 64];
    __shared__ __align__(16) ushort Bf[2][64 * 64];
    __shared__ __align__(16) ushort Bg[2][64 * 64];
    __shared__ float ta[64][65];
    __shared__ double bred[4][3];

    const int tid = threadIdx.x;
    const int lane = tid & 63;
    const int w = tid >> 6;
    const int wm = w & 1, wn = w >> 1;
    const int bid = blockIdx.x;
    const int j0 = (bid & 7) * 64;
    const int i0 = (bid >> 3) * 64;
    const int quad = lane >> 4;
    const int l15 = lane & 15;
    const int h7 = l15 & 7;

    f32x4 zero = {0.f, 0.f, 0.f, 0.f};
    f32x4 accf[2][2], accg[2][2];
#pragma unroll
    for (int mt = 0; mt < 2; ++mt)
#pragma unroll
        for (int nt = 0; nt < 2; ++nt) { accf[mt][nt] = zero; accg[mt][nt] = zero; }

    const int lr = lane >> 3;                 // 0..7 row-within-slab
    const int lc = ((lane & 7) ^ lr) * 8;     // XOR-swizzled fetch chunk

    auto stage = [&](int k0, int b) {
#pragma unroll
        for (int it = 0; it < 2; ++it) {
            const int base = it * 32 + w * 8;   // 8 rows per wave per round
            gload16(Kb + (size_t)(i0 + base + lr) * NN + k0 + lc, &As[b][base * 64]);
            gload16(fT + (size_t)(j0 + base + lr) * NN + k0 + lc, &Bf[b][base * 64]);
            gload16(gT + (size_t)(j0 + base + lr) * NN + k0 + lc, &Bg[b][base * 64]);
        }
    };

    stage(0, 0);
    __syncthreads();
    for (int step = 0; step < NN / 64; ++step) {
        const int cur = step & 1;
        if (step < NN / 64 - 1) stage((step + 1) * 64, cur ^ 1);
#pragma unroll
        for (int ks = 0; ks < 2; ++ks) {
            const int ch = ((ks * 4 + quad) ^ h7) * 8;   // swizzled read chunk
            short8 af[2];
#pragma unroll
            for (int mt = 0; mt < 2; ++mt)
                af[mt] = *(const short8*)&As[cur][(wm * 32 + mt * 16 + l15) * 64 + ch];
            short8 bfv[2], bgv[2];
#pragma unroll
            for (int nt = 0; nt < 2; ++nt) {
                bfv[nt] = *(const short8*)&Bf[cur][(wn * 32 + nt * 16 + l15) * 64 + ch];
                bgv[nt] = *(const short8*)&Bg[cur][(wn * 32 + nt * 16 + l15) * 64 + ch];
            }
#pragma unroll
            for (int mt = 0; mt < 2; ++mt)
#pragma unroll
                for (int nt = 0; nt < 2; ++nt) {
                    accf[mt][nt] = __builtin_amdgcn_mfma_f32_16x16x32_bf16(
                        af[mt], bfv[nt], accf[mt][nt], 0, 0, 0);
                    accg[mt][nt] = __builtin_amdgcn_mfma_f32_16x16x32_bf16(
                        af[mt], bgv[nt], accg[mt][nt], 0, 0, 0);
                }
        }
        __syncthreads();
    }

    // Fused epilogue.  C/D layout: col=lane&15, row=quad*4+reg.
    double t1 = 0.0, t2 = 0.0, t3 = 0.0;
#pragma unroll
    for (int mt = 0; mt < 2; ++mt)
#pragma unroll
        for (int nt = 0; nt < 2; ++nt) {
            const int il = wm * 32 + mt * 16 + quad * 4;  // local i
            const int jl = wn * 32 + nt * 16 + l15;       // local j
            const int ib = i0 + il;
            const int j = j0 + jl;
#pragma unroll
            for (int r = 0; r < 4; ++r) {
                float y1 = accf[mt][nt][r];
                float y2 = accg[mt][nt][r];
                float p = P[(size_t)(ib + r) * BB + j];
                float aij = p / y1;
                t1 += (double)(aij * y2);
                t2 += (double)(p * __logf(aij));
                t3 += (double)p;
                ta[il + r][jl] = aij;
            }
        }
    __syncthreads();
    {
        const int tx = tid & 15, ty = tid >> 4;
#pragma unroll
        for (int it = 0; it < 4; ++it) {
            int jrow = ty + it * 16;  // local j -> aT row (j0+jrow)
            ushort4v o = {f2bf(ta[tx * 4 + 0][jrow]), f2bf(ta[tx * 4 + 1][jrow]),
                          f2bf(ta[tx * 4 + 2][jrow]), f2bf(ta[tx * 4 + 3][jrow])};
            *(ushort4v*)&aT[(size_t)(j0 + jrow) * NN + i0 + tx * 4] = o;
        }
    }

    t1 = wave_sum(t1); t2 = wave_sum(t2); t3 = wave_sum(t3);
    if (lane == 0) { bred[w][0] = t1; bred[w][1] = t2; bred[w][2] = t3; }
    __syncthreads();
    if (tid == 0) {
        double a = 0, b = 0, c = 0;
#pragma unroll
        for (int ww = 0; ww < 4; ++ww) { a += bred[ww][0]; b += bred[ww][1]; c += bred[ww][2]; }
        parts[bid] = a;
        parts[512 + bid] = b;
        parts[1024 + bid] = c;
    }
}

// ---------------------------------------------------------------------------
// GEMM2 (MFMA, K-split 2, fused): partial S = KTb@a on 64x64 tiles;
// kl -= f*(1+L)*S (linear in S -> no partial buffer).  Grid 1024 (4/CU).
// ---------------------------------------------------------------------------
__global__ __launch_bounds__(256) void k_gemm2(const ushort* __restrict__ KTb,
                                               const ushort* __restrict__ aT,
                                               const float* __restrict__ U,
                                               const void* epsp, const void* lamp,
                                               double* __restrict__ parts) {
    __shared__ __align__(16) ushort As[2][64 * 64];
    __shared__ __align__(16) ushort Bs[2][64 * 64];
    __shared__ double bred[4];

    const float eps = scal_val(epsp), lam = scal_val(lamp);
    const float rr = lam / eps;
    const int tid = threadIdx.x;
    const int lane = tid & 63;
    const int w = tid >> 6;
    const int wm = w & 1, wn = w >> 1;
    const int bid = blockIdx.x;
    const int j0 = (bid & 7) * 64;
    const int i0 = ((bid >> 3) & 63) * 64;
    const int kh = bid >> 9;
    const int quad = lane >> 4;
    const int l15 = lane & 15;
    const int h7 = l15 & 7;

    f32x4 zero = {0.f, 0.f, 0.f, 0.f};
    f32x4 accs[2][2];
#pragma unroll
    for (int mt = 0; mt < 2; ++mt)
#pragma unroll
        for (int nt = 0; nt < 2; ++nt) accs[mt][nt] = zero;

    const int lr = lane >> 3;
    const int lc = ((lane & 7) ^ lr) * 8;

    auto stage = [&](int k0, int b) {
#pragma unroll
        for (int it = 0; it < 2; ++it) {
            const int base = it * 32 + w * 8;
            gload16(KTb + (size_t)(i0 + base + lr) * NN + k0 + lc, &As[b][base * 64]);
            gload16(aT + (size_t)(j0 + base + lr) * NN + k0 + lc, &Bs[b][base * 64]);
        }
    };

    const int kbase = kh * (NN / 2);
    stage(kbase, 0);
    __syncthreads();
    for (int step = 0; step < NN / 128; ++step) {
        const int cur = step & 1;
        if (step < NN / 128 - 1) stage(kbase + (step + 1) * 64, cur ^ 1);
#pragma unroll
        for (int ks = 0; ks < 2; ++ks) {
            const int ch = ((ks * 4 + quad) ^ h7) * 8;
            short8 af[2];
#pragma unroll
            for (int mt = 0; mt < 2; ++mt)
                af[mt] = *(const short8*)&As[cur][(wm * 32 + mt * 16 + l15) * 64 + ch];
            short8 bv[2];
#pragma unroll
            for (int nt = 0; nt < 2; ++nt)
                bv[nt] = *(const short8*)&Bs[cur][(wn * 32 + nt * 16 + l15) * 64 + ch];
#pragma unroll
            for (int mt = 0; mt < 2; ++mt)
#pragma unroll
                for (int nt = 0; nt < 2; ++nt)
                    accs[mt][nt] = __builtin_amdgcn_mfma_f32_16x16x32_bf16(
                        af[mt], bv[nt], accs[mt][nt], 0, 0, 0);
        }
        __syncthreads();
    }

    double klp = 0.0;
#pragma unroll
    for (int mt = 0; mt < 2; ++mt)
#pragma unroll
        for (int nt = 0; nt < 2; ++nt) {
            const int ib = i0 + wm * 32 + mt * 16 + quad * 4;
            const int j = j0 + wn * 32 + nt * 16 + l15;
#pragma unroll
            for (int r = 0; r < 4; ++r) {
                float s = accs[mt][nt][r];
                float u = U[(size_t)(ib + r) * BB + j];
                float L = __logf(lam / (lam - u));
                float fv = __expf(rr * L);
                klp -= (double)(fv * (1.0f + L) * s);
            }
        }

    klp = wave_sum(klp);
    if (lane == 0) bred[w] = klp;
    __syncthreads();
    if (tid == 0) parts[1536 + bid] = bred[0] + bred[1] + bred[2] + bred[3];
}

// ---------------------------------------------------------------------------
// Final: sum partials, out = eps*(t1+t2-t3) + lam*kl
// ---------------------------------------------------------------------------
__global__ __launch_bounds__(256) void k_final(const double* __restrict__ parts,
                                               const void* epsp, const void* lamp,
                                               float* __restrict__ out) {
    __shared__ double red[4][4];
    const int tid = threadIdx.x;
    const int lane = tid & 63, w = tid >> 6;
    double s0 = 0.0, s1 = 0.0, s2 = 0.0, s3 = 0.0;
    for (int i = tid; i < 512; i += 256) {
        s0 += parts[i];
        s1 += parts[512 + i];
        s2 += parts[1024 + i];
    }
    for (int i = tid; i < 1024; i += 256) s3 += parts[1536 + i];
    s0 = wave_sum(s0); s1 = wave_sum(s1); s2 = wave_sum(s2); s3 = wave_sum(s3);
    if (lane == 0) { red[w][0] = s0; red[w][1] = s1; red[w][2] = s2; red[w][3] = s3; }
    __syncthreads();
    if (tid == 0) {
        double t1 = 0, t2 = 0, t3 = 0, kl = 0;
#pragma unroll
        for (int ww = 0; ww < 4; ++ww) {
            t1 += red[ww][0]; t2 += red[ww][1]; t3 += red[ww][2]; kl += red[ww][3];
        }
        float eps = scal_val(epsp), lam = scal_val(lamp);
        out[0] = (float)((double)eps * (t1 + t2 - t3) + (double)lam * kl);
    }
}

extern "C" void kernel_launch(void* const* d_in, const int* in_sizes, int n_in,
                              void* d_out, int out_size, void* d_ws, size_t ws_size,
                              hipStream_t stream) {
    const float* U = (const float*)d_in[0];
    const float* P = (const float*)d_in[1];
    const float* K = (const float*)d_in[2];
    const void* epsp = d_in[3];
    const void* lamp = d_in[4];

    // ws: parts 20.5KB (pad to 64KB) | Kb 32M | KTb 32M | fT 4M | gT 4M | aT 4M
    double* parts = (double*)d_ws;
    char* base = (char*)d_ws + (64 << 10);
    ushort* Kb  = (ushort*)base;
    ushort* KTb = (ushort*)(base + ((size_t)32 << 20));
    ushort* fT  = (ushort*)(base + ((size_t)64 << 20));
    ushort* gT  = (ushort*)(base + ((size_t)68 << 20));
    ushort* aT  = (ushort*)(base + ((size_t)72 << 20));

    k_prep<<<4608, 256, 0, stream>>>(K, U, Kb, KTb, fT, gT, epsp, lamp);
    k_gemm1<<<512, 256, 0, stream>>>(Kb, fT, gT, P, aT, parts);
    k_gemm2<<<1024, 256, 0, stream>>>(KTb, aT, U, epsp, lamp, parts);
    k_final<<<1, 256, 0, stream>>>(parts, epsp, lamp, (float*)d_out);
}

// Round 6
// 191.941 us; speedup vs baseline: 1.1780x; 1.1780x over previous
//
#include <hip/hip_runtime.h>

#define NN 4096
#define BB 512

typedef __attribute__((ext_vector_type(4))) float f32x4;    // MFMA C/D frag
typedef unsigned short ushort;
typedef unsigned char uchar;
typedef unsigned int uint;

#define ASCALE 16384.0f            // 2^14 scale for a -> fp8
#define AINV   6.103515625e-05f    // 2^-14

__device__ __forceinline__ float scal_val(const void* p) {
    int b = *(const int*)p;
    if (b >= 1 && b <= 1000000) return (float)b;
    return __int_as_float(b);
}

// pack 4 floats -> 4 fp8 e4m3 bytes (OCP, RNE+sat via v_cvt_pk_fp8_f32)
__device__ __forceinline__ uint pack4_fp8(float a, float b, float c, float d) {
    int v = __builtin_amdgcn_cvt_pk_fp8_f32(a, b, 0, false);
    v = __builtin_amdgcn_cvt_pk_fp8_f32(c, d, v, true);
    return (uint)v;
}

__device__ __forceinline__ void gload16(const void* g, void* l) {
    __builtin_amdgcn_global_load_lds(
        (const __attribute__((address_space(1))) unsigned int*)g,
        (__attribute__((address_space(3))) unsigned int*)l, 16, 0, 0);
}

__device__ __forceinline__ double wave_sum(double v) {
#pragma unroll
    for (int s = 32; s > 0; s >>= 1) v += __shfl_down(v, s, 64);
    return v;
}

// LDS tile layout (fp8): row = 64 bytes (BK=64). Fetch-side XOR swizzle:
// lane L stages 16B unit (L&3)^(((L>>2)>>1)&3) of row L>>2, so logical unit
// v of row r lives at phys unit v^((r>>1)&3) -> frag reads are 2-way banked
// (free).  Frag addr for 8B chunk c of row r:
//   r*64 + (((c>>1)^((r>>1)&3))<<4) + ((c&1)<<3)

// Partials layout (doubles): [0,512) t1 | [512,1024) t2 | [1024,1536) t3
// | [1536,2048) kl.  Every slot written every call (no memset needed).

// ---------------------------------------------------------------------------
// Merged prep. Blocks [0,4096): K -> Kb (fp8) + KTb (fp8 transposed).
// Blocks [4096,4608): U -> fT, gT (fp8, transposed [j][k]).
// ---------------------------------------------------------------------------
__global__ __launch_bounds__(256) void k_prep(const float* __restrict__ K,
                                              const float* __restrict__ U,
                                              uchar* __restrict__ Kb,
                                              uchar* __restrict__ KTb,
                                              uchar* __restrict__ fT,
                                              uchar* __restrict__ gT,
                                              const void* epsp, const void* lamp) {
    __shared__ float tile[64][65];
    __shared__ float tg[64][65];
    const int t = threadIdx.x;
    const int tx = t & 15, ty = t >> 4;
    const int bid = blockIdx.x;

    if (bid < 4096) {
        const int c0 = (bid & 63) * 64, r0 = (bid >> 6) * 64;
#pragma unroll
        for (int it = 0; it < 4; ++it) {
            int row = ty + it * 16;
            float4 v = *(const float4*)&K[(size_t)(r0 + row) * NN + c0 + tx * 4];
            *(uint*)&Kb[(size_t)(r0 + row) * NN + c0 + tx * 4] =
                pack4_fp8(v.x, v.y, v.z, v.w);
            tile[row][tx * 4 + 0] = v.x;
            tile[row][tx * 4 + 1] = v.y;
            tile[row][tx * 4 + 2] = v.z;
            tile[row][tx * 4 + 3] = v.w;
        }
        __syncthreads();
#pragma unroll
        for (int it = 0; it < 4; ++it) {
            int row = ty + it * 16;  // col within tile -> KT row (c0+row)
            *(uint*)&KTb[(size_t)(c0 + row) * NN + r0 + tx * 4] =
                pack4_fp8(tile[tx * 4 + 0][row], tile[tx * 4 + 1][row],
                          tile[tx * 4 + 2][row], tile[tx * 4 + 3][row]);
        }
    } else {
        const int r = bid - 4096;
        const int c0 = (r & 7) * 64;   // U col tile (j)
        const int r0 = (r >> 3) * 64;  // U row tile (k)
        const float eps = scal_val(epsp), lam = scal_val(lamp);
        const float rr = lam / eps;
#pragma unroll
        for (int it = 0; it < 4; ++it) {
            int row = ty + it * 16;
            float4 v = *(const float4*)&U[(size_t)(r0 + row) * BB + c0 + tx * 4];
            float uu[4] = {v.x, v.y, v.z, v.w};
#pragma unroll
            for (int k = 0; k < 4; ++k) {
                float L = __logf(lam / (lam - uu[k]));
                float fl = rr * L;
                float fv = __expf(fl);
                tile[row][tx * 4 + k] = fv;
                tg[row][tx * 4 + k] = fv * fl;
            }
        }
        __syncthreads();
#pragma unroll
        for (int it = 0; it < 4; ++it) {
            int row = ty + it * 16;
            *(uint*)&fT[(size_t)(c0 + row) * NN + r0 + tx * 4] =
                pack4_fp8(tile[tx * 4 + 0][row], tile[tx * 4 + 1][row],
                          tile[tx * 4 + 2][row], tile[tx * 4 + 3][row]);
            *(uint*)&gT[(size_t)(c0 + row) * NN + r0 + tx * 4] =
                pack4_fp8(tg[tx * 4 + 0][row], tg[tx * 4 + 1][row],
                          tg[tx * 4 + 2][row], tg[tx * 4 + 3][row]);
        }
    }
}

// ---------------------------------------------------------------------------
// GEMM1 (fp8 MFMA, dual, K-split 2): partial Y1 = Kb@f, Y2 = Kb@g over K-half.
// Tile 128(M)x64(j), BK=64, dbuf, swizzled LDS.  Grid 512 (2 blocks/CU).
// ---------------------------------------------------------------------------
__global__ __launch_bounds__(256) void k_gemm1(const uchar* __restrict__ Kb,
                                               const uchar* __restrict__ fT,
                                               const uchar* __restrict__ gT,
                                               float* __restrict__ Y1p,
                                               float* __restrict__ Y2p) {
    __shared__ __align__(16) uchar As[2][128 * 64];
    __shared__ __align__(16) uchar Bf[2][64 * 64];
    __shared__ __align__(16) uchar Bg[2][64 * 64];

    const int tid = threadIdx.x;
    const int lane = tid & 63;
    const int w = tid >> 6;
    const int wm = w & 1, wn = w >> 1;
    const int bid = blockIdx.x;
    const int kh = bid & 1;                  // K-half
    const int i0 = ((bid >> 1) & 31) * 128;  // M panel
    const int j0 = (bid >> 6) * 64;          // j panel
    const int quad = lane >> 4;
    const int l15 = lane & 15;
    const int sw = (l15 >> 1) & 3;           // read-side row swizzle key

    f32x4 zero = {0.f, 0.f, 0.f, 0.f};
    f32x4 accf[4][2], accg[4][2];
#pragma unroll
    for (int mt = 0; mt < 4; ++mt)
#pragma unroll
        for (int nt = 0; nt < 2; ++nt) { accf[mt][nt] = zero; accg[mt][nt] = zero; }

    const int rl = lane >> 2;                       // 0..15 row within slab
    const int goff = ((lane & 3) ^ ((rl >> 1) & 3)) * 16;  // swizzled 16B unit

    auto stage = [&](int k0, int b) {
#pragma unroll
        for (int it = 0; it < 2; ++it) {
            const int rbase = w * 32 + it * 16;
            gload16(Kb + (size_t)(i0 + rbase + rl) * NN + k0 + goff,
                    &As[b][rbase * 64]);
        }
        const int rbase = w * 16;
        gload16(fT + (size_t)(j0 + rbase + rl) * NN + k0 + goff, &Bf[b][rbase * 64]);
        gload16(gT + (size_t)(j0 + rbase + rl) * NN + k0 + goff, &Bg[b][rbase * 64]);
    };

    const int kbase = kh * (NN / 2);
    stage(kbase, 0);
    __syncthreads();
    for (int step = 0; step < NN / 128; ++step) {   // 32 steps of BK=64
        const int cur = step & 1;
        if (step < NN / 128 - 1) stage(kbase + (step + 1) * 64, cur ^ 1);
#pragma unroll
        for (int ks = 0; ks < 2; ++ks) {
            const int c = ks * 4 + quad;                       // 8B chunk idx
            const int co = (((c >> 1) ^ sw) << 4) | ((c & 1) << 3);
            long af[4];
#pragma unroll
            for (int mt = 0; mt < 4; ++mt)
                af[mt] = *(const long*)&As[cur][(wm * 64 + mt * 16 + l15) * 64 + co];
            long bfv[2], bgv[2];
#pragma unroll
            for (int nt = 0; nt < 2; ++nt) {
                bfv[nt] = *(const long*)&Bf[cur][(wn * 32 + nt * 16 + l15) * 64 + co];
                bgv[nt] = *(const long*)&Bg[cur][(wn * 32 + nt * 16 + l15) * 64 + co];
            }
#pragma unroll
            for (int mt = 0; mt < 4; ++mt)
#pragma unroll
                for (int nt = 0; nt < 2; ++nt) {
                    accf[mt][nt] = __builtin_amdgcn_mfma_f32_16x16x32_fp8_fp8(
                        af[mt], bfv[nt], accf[mt][nt], 0, 0, 0);
                    accg[mt][nt] = __builtin_amdgcn_mfma_f32_16x16x32_fp8_fp8(
                        af[mt], bgv[nt], accg[mt][nt], 0, 0, 0);
                }
        }
        __syncthreads();
    }

    // Store fp32 partials [kh][i][j].  C/D layout: col=lane&15, row=quad*4+reg.
    float* o1 = Y1p + (size_t)kh * NN * BB;
    float* o2 = Y2p + (size_t)kh * NN * BB;
#pragma unroll
    for (int mt = 0; mt < 4; ++mt)
#pragma unroll
        for (int nt = 0; nt < 2; ++nt) {
            const int ib = i0 + wm * 64 + mt * 16 + quad * 4;
            const int j = j0 + wn * 32 + nt * 16 + l15;
#pragma unroll
            for (int r = 0; r < 4; ++r) {
                o1[(size_t)(ib + r) * BB + j] = accf[mt][nt][r];
                o2[(size_t)(ib + r) * BB + j] = accg[mt][nt][r];
            }
        }
}

// ---------------------------------------------------------------------------
// Epilogue: Y = sum of halves; a = P/Y1; t1 += a*Y2, t2 += P*log(a), t3 += P;
// aT (fp8 * 2^14, [j][i]) via LDS transpose.  Per-block partials, no atomics.
// ---------------------------------------------------------------------------
__global__ __launch_bounds__(256) void k_epi(const float* __restrict__ Y1p,
                                             const float* __restrict__ Y2p,
                                             const float* __restrict__ P,
                                             uchar* __restrict__ aT,
                                             double* __restrict__ parts) {
    __shared__ float ta[64][65];
    __shared__ double bred[4][3];
    const int t = threadIdx.x;
    const int lane = t & 63;
    const int w = t >> 6;
    const int tx = t & 15, ty = t >> 4;
    const int j0 = blockIdx.x * 64;
    const int i0 = blockIdx.y * 64;
    const int bid = blockIdx.y * 8 + blockIdx.x;
    const size_t H = (size_t)NN * BB;

    double t1 = 0.0, t2 = 0.0, t3 = 0.0;
#pragma unroll
    for (int it = 0; it < 4; ++it) {
        int row = ty + it * 16;
        size_t off = (size_t)(i0 + row) * BB + j0 + tx * 4;
        float4 a1 = *(const float4*)(Y1p + off);
        float4 b1 = *(const float4*)(Y1p + H + off);
        float4 a2 = *(const float4*)(Y2p + off);
        float4 b2 = *(const float4*)(Y2p + H + off);
        float4 p4 = *(const float4*)(P + off);
        float y1[4] = {a1.x + b1.x, a1.y + b1.y, a1.z + b1.z, a1.w + b1.w};
        float y2[4] = {a2.x + b2.x, a2.y + b2.y, a2.z + b2.z, a2.w + b2.w};
        float pv[4] = {p4.x, p4.y, p4.z, p4.w};
#pragma unroll
        for (int e = 0; e < 4; ++e) {
            float aij = pv[e] / y1[e];
            t1 += (double)(aij * y2[e]);
            t2 += (double)(pv[e] * __logf(aij));
            t3 += (double)pv[e];
            ta[row][tx * 4 + e] = aij * ASCALE;
        }
    }
    __syncthreads();
#pragma unroll
    for (int it = 0; it < 4; ++it) {
        int row = ty + it * 16;  // col within tile -> aT row (j0+row)
        *(uint*)&aT[(size_t)(j0 + row) * NN + i0 + tx * 4] =
            pack4_fp8(ta[tx * 4 + 0][row], ta[tx * 4 + 1][row],
                      ta[tx * 4 + 2][row], ta[tx * 4 + 3][row]);
    }

    t1 = wave_sum(t1); t2 = wave_sum(t2); t3 = wave_sum(t3);
    if (lane == 0) { bred[w][0] = t1; bred[w][1] = t2; bred[w][2] = t3; }
    __syncthreads();
    if (t == 0) {
        double a = 0, b = 0, c = 0;
#pragma unroll
        for (int ww = 0; ww < 4; ++ww) { a += bred[ww][0]; b += bred[ww][1]; c += bred[ww][2]; }
        parts[bid] = a;
        parts[512 + bid] = b;
        parts[1024 + bid] = c;
    }
}

// ---------------------------------------------------------------------------
// GEMM2 (fp8 MFMA, K-split 2): partial S' = KTb @ a' (a scaled by 2^14);
// kl -= f*(1+L)*S'*2^-14.  Tile 128x64, grid 512, no atomics.
// ---------------------------------------------------------------------------
__global__ __launch_bounds__(256) void k_gemm2(const uchar* __restrict__ KTb,
                                               const uchar* __restrict__ aT,
                                               const float* __restrict__ U,
                                               const void* epsp, const void* lamp,
                                               double* __restrict__ parts) {
    __shared__ __align__(16) uchar As[2][128 * 64];
    __shared__ __align__(16) uchar Bs[2][64 * 64];
    __shared__ double bred[4];

    const float eps = scal_val(epsp), lam = scal_val(lamp);
    const float rr = lam / eps;
    const int tid = threadIdx.x;
    const int lane = tid & 63;
    const int w = tid >> 6;
    const int wm = w & 1, wn = w >> 1;
    const int bid = blockIdx.x;
    const int kh = bid & 1;
    const int i0 = ((bid >> 1) & 31) * 128;
    const int j0 = (bid >> 6) * 64;
    const int quad = lane >> 4;
    const int l15 = lane & 15;
    const int sw = (l15 >> 1) & 3;

    f32x4 zero = {0.f, 0.f, 0.f, 0.f};
    f32x4 accs[4][2];
#pragma unroll
    for (int mt = 0; mt < 4; ++mt)
#pragma unroll
        for (int nt = 0; nt < 2; ++nt) accs[mt][nt] = zero;

    const int rl = lane >> 2;
    const int goff = ((lane & 3) ^ ((rl >> 1) & 3)) * 16;

    auto stage = [&](int k0, int b) {
#pragma unroll
        for (int it = 0; it < 2; ++it) {
            const int rbase = w * 32 + it * 16;
            gload16(KTb + (size_t)(i0 + rbase + rl) * NN + k0 + goff,
                    &As[b][rbase * 64]);
        }
        const int rbase = w * 16;
        gload16(aT + (size_t)(j0 + rbase + rl) * NN + k0 + goff, &Bs[b][rbase * 64]);
    };

    const int kbase = kh * (NN / 2);
    stage(kbase, 0);
    __syncthreads();
    for (int step = 0; step < NN / 128; ++step) {
        const int cur = step & 1;
        if (step < NN / 128 - 1) stage(kbase + (step + 1) * 64, cur ^ 1);
#pragma unroll
        for (int ks = 0; ks < 2; ++ks) {
            const int c = ks * 4 + quad;
            const int co = (((c >> 1) ^ sw) << 4) | ((c & 1) << 3);
            long af[4];
#pragma unroll
            for (int mt = 0; mt < 4; ++mt)
                af[mt] = *(const long*)&As[cur][(wm * 64 + mt * 16 + l15) * 64 + co];
            long bv[2];
#pragma unroll
            for (int nt = 0; nt < 2; ++nt)
                bv[nt] = *(const long*)&Bs[cur][(wn * 32 + nt * 16 + l15) * 64 + co];
#pragma unroll
            for (int mt = 0; mt < 4; ++mt)
#pragma unroll
                for (int nt = 0; nt < 2; ++nt)
                    accs[mt][nt] = __builtin_amdgcn_mfma_f32_16x16x32_fp8_fp8(
                        af[mt], bv[nt], accs[mt][nt], 0, 0, 0);
        }
        __syncthreads();
    }

    double klp = 0.0;
#pragma unroll
    for (int mt = 0; mt < 4; ++mt)
#pragma unroll
        for (int nt = 0; nt < 2; ++nt) {
            const int ib = i0 + wm * 64 + mt * 16 + quad * 4;
            const int j = j0 + wn * 32 + nt * 16 + l15;
#pragma unroll
            for (int r = 0; r < 4; ++r) {
                float s = accs[mt][nt][r] * AINV;
                float u = U[(size_t)(ib + r) * BB + j];
                float L = __logf(lam / (lam - u));
                float fv = __expf(rr * L);
                klp -= (double)(fv * (1.0f + L) * s);
            }
        }

    klp = wave_sum(klp);
    if (lane == 0) bred[w] = klp;
    __syncthreads();
    if (tid == 0) parts[1536 + bid] = bred[0] + bred[1] + bred[2] + bred[3];
}

// ---------------------------------------------------------------------------
// Final: sum partials, out = eps*(t1+t2-t3) + lam*kl
// ---------------------------------------------------------------------------
__global__ __launch_bounds__(256) void k_final(const double* __restrict__ parts,
                                               const void* epsp, const void* lamp,
                                               float* __restrict__ out) {
    __shared__ double red[4][4];
    const int tid = threadIdx.x;
    const int lane = tid & 63, w = tid >> 6;
    double s0 = 0.0, s1 = 0.0, s2 = 0.0, s3 = 0.0;
    for (int i = tid; i < 512; i += 256) {
        s0 += parts[i];
        s1 += parts[512 + i];
        s2 += parts[1024 + i];
        s3 += parts[1536 + i];
    }
    s0 = wave_sum(s0); s1 = wave_sum(s1); s2 = wave_sum(s2); s3 = wave_sum(s3);
    if (lane == 0) { red[w][0] = s0; red[w][1] = s1; red[w][2] = s2; red[w][3] = s3; }
    __syncthreads();
    if (tid == 0) {
        double t1 = 0, t2 = 0, t3 = 0, kl = 0;
#pragma unroll
        for (int ww = 0; ww < 4; ++ww) {
            t1 += red[ww][0]; t2 += red[ww][1]; t3 += red[ww][2]; kl += red[ww][3];
        }
        float eps = scal_val(epsp), lam = scal_val(lamp);
        out[0] = (float)((double)eps * (t1 + t2 - t3) + (double)lam * kl);
    }
}

extern "C" void kernel_launch(void* const* d_in, const int* in_sizes, int n_in,
                              void* d_out, int out_size, void* d_ws, size_t ws_size,
                              hipStream_t stream) {
    const float* U = (const float*)d_in[0];
    const float* P = (const float*)d_in[1];
    const float* K = (const float*)d_in[2];
    const void* epsp = d_in[3];
    const void* lamp = d_in[4];

    // ws: parts 16KB (pad 64KB) | Kb 16M | KTb 16M | fT 2M | gT 2M | aT 2M
    //     | Y1p 16M | Y2p 16M
    double* parts = (double*)d_ws;
    char* base = (char*)d_ws + (64 << 10);
    uchar* Kb  = (uchar*)base;
    uchar* KTb = (uchar*)(base + ((size_t)16 << 20));
    uchar* fT  = (uchar*)(base + ((size_t)32 << 20));
    uchar* gT  = (uchar*)(base + ((size_t)34 << 20));
    uchar* aT  = (uchar*)(base + ((size_t)36 << 20));
    float* Y1p = (float*)(base + ((size_t)38 << 20));
    float* Y2p = (float*)(base + ((size_t)54 << 20));

    k_prep<<<4608, 256, 0, stream>>>(K, U, Kb, KTb, fT, gT, epsp, lamp);
    k_gemm1<<<512, 256, 0, stream>>>(Kb, fT, gT, Y1p, Y2p);
    k_epi<<<dim3(8, 64), 256, 0, stream>>>(Y1p, Y2p, P, aT, parts);
    k_gemm2<<<512, 256, 0, stream>>>(KTb, aT, U, epsp, lamp, parts);
    k_final<<<1, 256, 0, stream>>>(parts, epsp, lamp, (float*)d_out);
}

// Round 7
// 171.232 us; speedup vs baseline: 1.3204x; 1.1209x over previous
//
#include <hip/hip_runtime.h>

#define NN 4096
#define BB 512

typedef __attribute__((ext_vector_type(4))) float f32x4;    // MFMA C/D frag
typedef __attribute__((ext_vector_type(2))) long long2v;    // 16B LDS read
typedef unsigned short ushort;
typedef unsigned char uchar;
typedef unsigned int uint;

#define ASCALE 16384.0f            // 2^14 scale for a -> fp8
#define AINV   6.103515625e-05f    // 2^-14

__device__ __forceinline__ float scal_val(const void* p) {
    int b = *(const int*)p;
    if (b >= 1 && b <= 1000000) return (float)b;
    return __int_as_float(b);
}

// pack 4 floats -> 4 fp8 e4m3 bytes (OCP, RNE+sat via v_cvt_pk_fp8_f32)
__device__ __forceinline__ uint pack4_fp8(float a, float b, float c, float d) {
    int v = __builtin_amdgcn_cvt_pk_fp8_f32(a, b, 0, false);
    v = __builtin_amdgcn_cvt_pk_fp8_f32(c, d, v, true);
    return (uint)v;
}

__device__ __forceinline__ void gload16(const void* g, void* l) {
    __builtin_amdgcn_global_load_lds(
        (const __attribute__((address_space(1))) unsigned int*)g,
        (__attribute__((address_space(3))) unsigned int*)l, 16, 0, 0);
}

__device__ __forceinline__ double wave_sum(double v) {
#pragma unroll
    for (int s = 32; s > 0; s >>= 1) v += __shfl_down(v, s, 64);
    return v;
}

// k-permutation within each 64-byte k-group: orig chunk c=k>>3 (ks=c>>2,
// quad=c&3) stored at pos quad*16 + ks*8 + (k&7).  One b128 at unit `quad`
// yields ks0 in bytes[0:8) and ks1 in bytes[8:16).
__device__ __forceinline__ int kperm(int kk) {   // kk in [0,64), mult of 4
    int c = kk >> 3;
    return (c & 3) * 16 + (c >> 2) * 8 + (kk & 7);
}

// Partials (doubles): [0,1024) t1 | [1024,2048) kl | [2048,2560) t2
// | [2560,3072) t3.  Every slot written every call (no memset).

// ---------------------------------------------------------------------------
// Merged prep. Blocks [0,4096): K -> Kb (fp8, k-permuted) + KTb (fp8,
// transposed, k-permuted).  Blocks [4096,4608): U -> fT (fp8 [j][k] permuted).
// ---------------------------------------------------------------------------
__global__ __launch_bounds__(256) void k_prep(const float* __restrict__ K,
                                              const float* __restrict__ U,
                                              uchar* __restrict__ Kb,
                                              uchar* __restrict__ KTb,
                                              uchar* __restrict__ fT,
                                              const void* epsp, const void* lamp) {
    __shared__ float tile[64][65];
    const int t = threadIdx.x;
    const int tx = t & 15, ty = t >> 4;
    const int bid = blockIdx.x;
    const int pp = kperm(tx * 4);

    if (bid < 4096) {
        const int c0 = (bid & 63) * 64, r0 = (bid >> 6) * 64;
#pragma unroll
        for (int it = 0; it < 4; ++it) {
            int row = ty + it * 16;
            float4 v = *(const float4*)&K[(size_t)(r0 + row) * NN + c0 + tx * 4];
            *(uint*)&Kb[(size_t)(r0 + row) * NN + c0 + pp] =
                pack4_fp8(v.x, v.y, v.z, v.w);
            tile[row][tx * 4 + 0] = v.x;
            tile[row][tx * 4 + 1] = v.y;
            tile[row][tx * 4 + 2] = v.z;
            tile[row][tx * 4 + 3] = v.w;
        }
        __syncthreads();
#pragma unroll
        for (int it = 0; it < 4; ++it) {
            int row = ty + it * 16;  // col within tile -> KT row (c0+row)
            *(uint*)&KTb[(size_t)(c0 + row) * NN + r0 + pp] =
                pack4_fp8(tile[tx * 4 + 0][row], tile[tx * 4 + 1][row],
                          tile[tx * 4 + 2][row], tile[tx * 4 + 3][row]);
        }
    } else {
        const int r = bid - 4096;
        const int c0 = (r & 7) * 64;   // U col tile (j)
        const int r0 = (r >> 3) * 64;  // U row tile (k)
        const float eps = scal_val(epsp), lam = scal_val(lamp);
        const float rr = lam / eps;
#pragma unroll
        for (int it = 0; it < 4; ++it) {
            int row = ty + it * 16;
            float4 v = *(const float4*)&U[(size_t)(r0 + row) * BB + c0 + tx * 4];
            float uu[4] = {v.x, v.y, v.z, v.w};
#pragma unroll
            for (int k = 0; k < 4; ++k) {
                float L = __logf(lam / (lam - uu[k]));
                tile[row][tx * 4 + k] = __expf(rr * L);
            }
        }
        __syncthreads();
#pragma unroll
        for (int it = 0; it < 4; ++it) {
            int row = ty + it * 16;
            *(uint*)&fT[(size_t)(c0 + row) * NN + r0 + pp] =
                pack4_fp8(tile[tx * 4 + 0][row], tile[tx * 4 + 1][row],
                          tile[tx * 4 + 2][row], tile[tx * 4 + 3][row]);
        }
    }
}

// ---------------------------------------------------------------------------
// GEMM1 (fp8 MFMA, K-split 4): partial Y1 = Kb@f over K-quarter.
// Tile 128(M)x64(j), BK=64, dbuf, permuted-b128 LDS.  Grid 1024 (4/CU).
// ---------------------------------------------------------------------------
__global__ __launch_bounds__(256) void k_gemm1(const uchar* __restrict__ Kb,
                                               const uchar* __restrict__ fT,
                                               float* __restrict__ Y1p) {
    __shared__ __align__(16) uchar As[2][128 * 64];   // 16 KB
    __shared__ __align__(16) uchar Bf[2][64 * 64];    //  8 KB

    const int tid = threadIdx.x;
    const int lane = tid & 63;
    const int w = tid >> 6;
    const int wm = w & 1, wn = w >> 1;
    const int bid = blockIdx.x;
    const int kh = bid & 3;                  // K-quarter
    const int i0 = ((bid >> 2) & 31) * 128;  // M panel
    const int j0 = (bid >> 7) * 64;          // j panel
    const int quad = lane >> 4;
    const int l15 = lane & 15;
    const int sw = (l15 >> 1) & 3;           // read-side unit swizzle key

    f32x4 zero = {0.f, 0.f, 0.f, 0.f};
    f32x4 acc[4][2];
#pragma unroll
    for (int mt = 0; mt < 4; ++mt)
#pragma unroll
        for (int nt = 0; nt < 2; ++nt) acc[mt][nt] = zero;

    const int rl = lane >> 2;                              // 0..15 row in slab
    const int goff = ((lane & 3) ^ ((lane >> 3) & 3)) * 16; // swizzled unit

    auto stage = [&](int k0, int b) {
#pragma unroll
        for (int it = 0; it < 2; ++it) {
            const int rbase = w * 32 + it * 16;
            gload16(Kb + (size_t)(i0 + rbase + rl) * NN + k0 + goff,
                    &As[b][rbase * 64]);
        }
        gload16(fT + (size_t)(j0 + w * 16 + rl) * NN + k0 + goff,
                &Bf[b][(w * 16) * 64]);
    };

    const int kbase = kh * (NN / 4);
    stage(kbase, 0);
    __syncthreads();
    const int uoff = ((quad ^ sw) << 4);
    for (int step = 0; step < NN / 256; ++step) {   // 16 steps of BK=64
        const int cur = step & 1;
        if (step < NN / 256 - 1) stage(kbase + (step + 1) * 64, cur ^ 1);
        long2v av[4], bv[2];
#pragma unroll
        for (int mt = 0; mt < 4; ++mt)
            av[mt] = *(const long2v*)&As[cur][(wm * 64 + mt * 16 + l15) * 64 + uoff];
#pragma unroll
        for (int nt = 0; nt < 2; ++nt)
            bv[nt] = *(const long2v*)&Bf[cur][(wn * 32 + nt * 16 + l15) * 64 + uoff];
#pragma unroll
        for (int mt = 0; mt < 4; ++mt)
#pragma unroll
            for (int nt = 0; nt < 2; ++nt) {
                acc[mt][nt] = __builtin_amdgcn_mfma_f32_16x16x32_fp8_fp8(
                    av[mt].x, bv[nt].x, acc[mt][nt], 0, 0, 0);
                acc[mt][nt] = __builtin_amdgcn_mfma_f32_16x16x32_fp8_fp8(
                    av[mt].y, bv[nt].y, acc[mt][nt], 0, 0, 0);
            }
        __syncthreads();
    }

    // Store fp32 partial [kh][i][j].  C/D layout: col=lane&15, row=quad*4+reg.
    float* o1 = Y1p + (size_t)kh * NN * BB;
#pragma unroll
    for (int mt = 0; mt < 4; ++mt)
#pragma unroll
        for (int nt = 0; nt < 2; ++nt) {
            const int ib = i0 + wm * 64 + mt * 16 + quad * 4;
            const int j = j0 + wn * 32 + nt * 16 + l15;
#pragma unroll
            for (int r = 0; r < 4; ++r)
                o1[(size_t)(ib + r) * BB + j] = acc[mt][nt][r];
        }
}

// ---------------------------------------------------------------------------
// Epilogue: Y1 = sum of 4 quarters; a = P/Y1; t2 += P*log(a), t3 += P;
// aT (fp8 * 2^14, [j][i] k-permuted) via LDS transpose.  No atomics.
// ---------------------------------------------------------------------------
__global__ __launch_bounds__(256) void k_epi(const float* __restrict__ Y1p,
                                             const float* __restrict__ P,
                                             uchar* __restrict__ aT,
                                             double* __restrict__ parts) {
    __shared__ float ta[64][65];
    __shared__ double bred[4][2];
    const int t = threadIdx.x;
    const int lane = t & 63;
    const int w = t >> 6;
    const int tx = t & 15, ty = t >> 4;
    const int j0 = blockIdx.x * 64;
    const int i0 = blockIdx.y * 64;
    const int bid = blockIdx.y * 8 + blockIdx.x;
    const size_t H = (size_t)NN * BB;
    const int pp = kperm(tx * 4);

    double t2 = 0.0, t3 = 0.0;
#pragma unroll
    for (int it = 0; it < 4; ++it) {
        int row = ty + it * 16;
        size_t off = (size_t)(i0 + row) * BB + j0 + tx * 4;
        float4 a1 = *(const float4*)(Y1p + off);
        float4 b1 = *(const float4*)(Y1p + H + off);
        float4 c1 = *(const float4*)(Y1p + 2 * H + off);
        float4 d1 = *(const float4*)(Y1p + 3 * H + off);
        float4 p4 = *(const float4*)(P + off);
        float y1[4] = {a1.x + b1.x + c1.x + d1.x, a1.y + b1.y + c1.y + d1.y,
                       a1.z + b1.z + c1.z + d1.z, a1.w + b1.w + c1.w + d1.w};
        float pv[4] = {p4.x, p4.y, p4.z, p4.w};
#pragma unroll
        for (int e = 0; e < 4; ++e) {
            float aij = pv[e] / y1[e];
            t2 += (double)(pv[e] * __logf(aij));
            t3 += (double)pv[e];
            ta[row][tx * 4 + e] = aij * ASCALE;
        }
    }
    __syncthreads();
#pragma unroll
    for (int it = 0; it < 4; ++it) {
        int row = ty + it * 16;  // col within tile -> aT row (j0+row)
        *(uint*)&aT[(size_t)(j0 + row) * NN + i0 + pp] =
            pack4_fp8(ta[tx * 4 + 0][row], ta[tx * 4 + 1][row],
                      ta[tx * 4 + 2][row], ta[tx * 4 + 3][row]);
    }

    t2 = wave_sum(t2); t3 = wave_sum(t3);
    if (lane == 0) { bred[w][0] = t2; bred[w][1] = t3; }
    __syncthreads();
    if (t == 0) {
        double b = 0, c = 0;
#pragma unroll
        for (int ww = 0; ww < 4; ++ww) { b += bred[ww][0]; c += bred[ww][1]; }
        parts[2048 + bid] = b;
        parts[2560 + bid] = c;
    }
}

// ---------------------------------------------------------------------------
// GEMM2 (fp8 MFMA, K-split 4): partial S' = KTb @ a' (a scaled 2^14).
// Epilogue (both linear in S): t1 += g*S, kl -= f*(1+L)*S, with
// f,L,g=f*rr*L recomputed from U.  Grid 1024, no atomics.
// ---------------------------------------------------------------------------
__global__ __launch_bounds__(256) void k_gemm2(const uchar* __restrict__ KTb,
                                               const uchar* __restrict__ aT,
                                               const float* __restrict__ U,
                                               const void* epsp, const void* lamp,
                                               double* __restrict__ parts) {
    __shared__ __align__(16) uchar As[2][128 * 64];
    __shared__ __align__(16) uchar Bs[2][64 * 64];
    __shared__ double bred[4][2];

    const float eps = scal_val(epsp), lam = scal_val(lamp);
    const float rr = lam / eps;
    const int tid = threadIdx.x;
    const int lane = tid & 63;
    const int w = tid >> 6;
    const int wm = w & 1, wn = w >> 1;
    const int bid = blockIdx.x;
    const int kh = bid & 3;
    const int i0 = ((bid >> 2) & 31) * 128;
    const int j0 = (bid >> 7) * 64;
    const int quad = lane >> 4;
    const int l15 = lane & 15;
    const int sw = (l15 >> 1) & 3;

    f32x4 zero = {0.f, 0.f, 0.f, 0.f};
    f32x4 acc[4][2];
#pragma unroll
    for (int mt = 0; mt < 4; ++mt)
#pragma unroll
        for (int nt = 0; nt < 2; ++nt) acc[mt][nt] = zero;

    const int rl = lane >> 2;
    const int goff = ((lane & 3) ^ ((lane >> 3) & 3)) * 16;

    auto stage = [&](int k0, int b) {
#pragma unroll
        for (int it = 0; it < 2; ++it) {
            const int rbase = w * 32 + it * 16;
            gload16(KTb + (size_t)(i0 + rbase + rl) * NN + k0 + goff,
                    &As[b][rbase * 64]);
        }
        gload16(aT + (size_t)(j0 + w * 16 + rl) * NN + k0 + goff,
                &Bs[b][(w * 16) * 64]);
    };

    const int kbase = kh * (NN / 4);
    stage(kbase, 0);
    __syncthreads();
    const int uoff = ((quad ^ sw) << 4);
    for (int step = 0; step < NN / 256; ++step) {
        const int cur = step & 1;
        if (step < NN / 256 - 1) stage(kbase + (step + 1) * 64, cur ^ 1);
        long2v av[4], bv[2];
#pragma unroll
        for (int mt = 0; mt < 4; ++mt)
            av[mt] = *(const long2v*)&As[cur][(wm * 64 + mt * 16 + l15) * 64 + uoff];
#pragma unroll
        for (int nt = 0; nt < 2; ++nt)
            bv[nt] = *(const long2v*)&Bs[cur][(wn * 32 + nt * 16 + l15) * 64 + uoff];
#pragma unroll
        for (int mt = 0; mt < 4; ++mt)
#pragma unroll
            for (int nt = 0; nt < 2; ++nt) {
                acc[mt][nt] = __builtin_amdgcn_mfma_f32_16x16x32_fp8_fp8(
                    av[mt].x, bv[nt].x, acc[mt][nt], 0, 0, 0);
                acc[mt][nt] = __builtin_amdgcn_mfma_f32_16x16x32_fp8_fp8(
                    av[mt].y, bv[nt].y, acc[mt][nt], 0, 0, 0);
            }
        __syncthreads();
    }

    double t1p = 0.0, klp = 0.0;
#pragma unroll
    for (int mt = 0; mt < 4; ++mt)
#pragma unroll
        for (int nt = 0; nt < 2; ++nt) {
            const int ib = i0 + wm * 64 + mt * 16 + quad * 4;  // k index
            const int j = j0 + wn * 32 + nt * 16 + l15;
#pragma unroll
            for (int r = 0; r < 4; ++r) {
                float s = acc[mt][nt][r] * AINV;
                float u = U[(size_t)(ib + r) * BB + j];
                float L = __logf(lam / (lam - u));
                float fv = __expf(rr * L);
                t1p += (double)(fv * rr * L * s);       // g*S
                klp -= (double)(fv * (1.0f + L) * s);   // -f*(1+L)*S
            }
        }

    t1p = wave_sum(t1p); klp = wave_sum(klp);
    if (lane == 0) { bred[w][0] = t1p; bred[w][1] = klp; }
    __syncthreads();
    if (tid == 0) {
        double a = 0, b = 0;
#pragma unroll
        for (int ww = 0; ww < 4; ++ww) { a += bred[ww][0]; b += bred[ww][1]; }
        parts[bid] = a;
        parts[1024 + bid] = b;
    }
}

// ---------------------------------------------------------------------------
// Final: sum partials, out = eps*(t1+t2-t3) + lam*kl
// ---------------------------------------------------------------------------
__global__ __launch_bounds__(256) void k_final(const double* __restrict__ parts,
                                               const void* epsp, const void* lamp,
                                               float* __restrict__ out) {
    __shared__ double red[4][4];
    const int tid = threadIdx.x;
    const int lane = tid & 63, w = tid >> 6;
    double s0 = 0.0, s1 = 0.0, s2 = 0.0, s3 = 0.0;
    for (int i = tid; i < 1024; i += 256) {
        s0 += parts[i];          // t1
        s1 += parts[1024 + i];   // kl
    }
    for (int i = tid; i < 512; i += 256) {
        s2 += parts[2048 + i];   // t2
        s3 += parts[2560 + i];   // t3
    }
    s0 = wave_sum(s0); s1 = wave_sum(s1); s2 = wave_sum(s2); s3 = wave_sum(s3);
    if (lane == 0) { red[w][0] = s0; red[w][1] = s1; red[w][2] = s2; red[w][3] = s3; }
    __syncthreads();
    if (tid == 0) {
        double t1 = 0, kl = 0, t2 = 0, t3 = 0;
#pragma unroll
        for (int ww = 0; ww < 4; ++ww) {
            t1 += red[ww][0]; kl += red[ww][1]; t2 += red[ww][2]; t3 += red[ww][3];
        }
        float eps = scal_val(epsp), lam = scal_val(lamp);
        out[0] = (float)((double)eps * (t1 + t2 - t3) + (double)lam * kl);
    }
}

extern "C" void kernel_launch(void* const* d_in, const int* in_sizes, int n_in,
                              void* d_out, int out_size, void* d_ws, size_t ws_size,
                              hipStream_t stream) {
    const float* U = (const float*)d_in[0];
    const float* P = (const float*)d_in[1];
    const float* K = (const float*)d_in[2];
    const void* epsp = d_in[3];
    const void* lamp = d_in[4];

    // ws: parts 24KB (pad 64KB) | Kb 16M | KTb 16M | fT 2M | aT 2M | Y1p 32M
    double* parts = (double*)d_ws;
    char* base = (char*)d_ws + (64 << 10);
    uchar* Kb  = (uchar*)base;
    uchar* KTb = (uchar*)(base + ((size_t)16 << 20));
    uchar* fT  = (uchar*)(base + ((size_t)32 << 20));
    uchar* aT  = (uchar*)(base + ((size_t)34 << 20));
    float* Y1p = (float*)(base + ((size_t)36 << 20));

    k_prep<<<4608, 256, 0, stream>>>(K, U, Kb, KTb, fT, epsp, lamp);
    k_gemm1<<<1024, 256, 0, stream>>>(Kb, fT, Y1p);
    k_epi<<<dim3(8, 64), 256, 0, stream>>>(Y1p, P, aT, parts);
    k_gemm2<<<1024, 256, 0, stream>>>(KTb, aT, U, epsp, lamp, parts);
    k_final<<<1, 256, 0, stream>>>(parts, epsp, lamp, (float*)d_out);
}